// Round 1
// baseline (24.720 us; speedup 1.0000x reference)
//
#include <hip/hip_runtime.h>

// EMA-of-changes, closed form:
//   out[n] = x[T-1][n] + sum_{t=t0}^{T-2} (1-w) w^{T-2-t} (x[t+1][n]-x[t][n])
// Telescoped to one coefficient per row r in [rlo, T-1]:
//   g[T-1]        = 1 + (1-w)
//   g[r] (middle) = -(1-w)^2 * w^(T-2-r)
//   g[rlo]        = -(1-w)   * w^(T-2-rlo)
// Truncation: w=0.9 => w^511 ~ 5e-24, so keeping the last KEEP_ROWS=512 rows
// is exact to f32. Reads 32MB instead of 256MB.

#define WEMA 0.9f
#define KEEP_ROWS 512
#define CHUNK_ROWS 16

__device__ __forceinline__ float row_coeff(int r, int rlo, int T) {
    if (r == T - 1) return 2.0f - WEMA;                 // 1 + (1-w)
    float p = __powf(WEMA, (float)(T - 2 - r));         // w^(T-2-r)
    float s = (r == rlo) ? (1.0f - WEMA)
                         : (1.0f - WEMA) * (1.0f - WEMA);
    return -s * p;
}

__global__ void ema_partial(const float* __restrict__ x, float* __restrict__ ws,
                            int T, int N4, int rlo) {
    int col4 = blockIdx.x * blockDim.x + threadIdx.x;   // float4 column index
    if (col4 >= N4) return;
    int rbeg = rlo + blockIdx.y * CHUNK_ROWS;
    int rend = rbeg + CHUNK_ROWS;
    if (rend > T) rend = T;
    const float4* x4 = reinterpret_cast<const float4*>(x);
    float4 acc = make_float4(0.f, 0.f, 0.f, 0.f);
    #pragma unroll 4
    for (int r = rbeg; r < rend; ++r) {
        float g = row_coeff(r, rlo, T);
        float4 v = x4[(size_t)r * N4 + col4];
        acc.x += g * v.x; acc.y += g * v.y;
        acc.z += g * v.z; acc.w += g * v.w;
    }
    reinterpret_cast<float4*>(ws)[(size_t)blockIdx.y * N4 + col4] = acc;
}

__global__ void ema_reduce(const float* __restrict__ ws, float* __restrict__ out,
                           int N4, int nchunks) {
    int col4 = blockIdx.x * blockDim.x + threadIdx.x;
    if (col4 >= N4) return;
    const float4* w4 = reinterpret_cast<const float4*>(ws);
    float4 acc = make_float4(0.f, 0.f, 0.f, 0.f);
    for (int c = 0; c < nchunks; ++c) {
        float4 v = w4[(size_t)c * N4 + col4];
        acc.x += v.x; acc.y += v.y; acc.z += v.z; acc.w += v.w;
    }
    reinterpret_cast<float4*>(out)[col4] = acc;
}

// ---- fallback path (only if ws_size is too small): zero + atomicAdd ----
__global__ void zero_out(float* __restrict__ out, int N) {
    int i = blockIdx.x * blockDim.x + threadIdx.x;
    if (i < N) out[i] = 0.f;
}

__global__ void ema_partial_atomic(const float* __restrict__ x, float* __restrict__ out,
                                   int T, int N4, int rlo) {
    int col4 = blockIdx.x * blockDim.x + threadIdx.x;
    if (col4 >= N4) return;
    int rbeg = rlo + blockIdx.y * CHUNK_ROWS;
    int rend = rbeg + CHUNK_ROWS;
    if (rend > T) rend = T;
    const float4* x4 = reinterpret_cast<const float4*>(x);
    float4 acc = make_float4(0.f, 0.f, 0.f, 0.f);
    for (int r = rbeg; r < rend; ++r) {
        float g = row_coeff(r, rlo, T);
        float4 v = x4[(size_t)r * N4 + col4];
        acc.x += g * v.x; acc.y += g * v.y;
        acc.z += g * v.z; acc.w += g * v.w;
    }
    atomicAdd(&out[col4 * 4 + 0], acc.x);
    atomicAdd(&out[col4 * 4 + 1], acc.y);
    atomicAdd(&out[col4 * 4 + 2], acc.z);
    atomicAdd(&out[col4 * 4 + 3], acc.w);
}

extern "C" void kernel_launch(void* const* d_in, const int* in_sizes, int n_in,
                              void* d_out, int out_size, void* d_ws, size_t ws_size,
                              hipStream_t stream) {
    const float* x = (const float*)d_in[0];
    float* out = (float*)d_out;
    float* ws = (float*)d_ws;

    const int N = out_size;                 // 16384
    const int T = in_sizes[0] / N;          // 4096
    const int N4 = N >> 2;                  // 4096 (N is a multiple of 4)

    int rlo = T - KEEP_ROWS;                // first row we keep
    if (rlo < 0) rlo = 0;
    const int nrows = T - rlo;              // 512
    const int nchunks = (nrows + CHUNK_ROWS - 1) / CHUNK_ROWS;  // 32

    const int threads = 256;
    dim3 grid((N4 + threads - 1) / threads, nchunks);           // 16 x 32

    size_t ws_needed = (size_t)nchunks * N * sizeof(float);     // 2 MB
    if (ws_size >= ws_needed) {
        ema_partial<<<grid, threads, 0, stream>>>(x, ws, T, N4, rlo);
        ema_reduce<<<(N4 + threads - 1) / threads, threads, 0, stream>>>(ws, out, N4, nchunks);
    } else {
        zero_out<<<(N + threads - 1) / threads, threads, 0, stream>>>(out, N);
        ema_partial_atomic<<<grid, threads, 0, stream>>>(x, out, T, N4, rlo);
    }
}

// Round 2
// 9.728 us; speedup vs baseline: 2.5410x; 2.5410x over previous
//
#include <hip/hip_runtime.h>

// EMA-of-changes, closed form, telescoped to one coefficient per row:
//   out[n] = sum_r g[r] * x[r][n], over the last KEEP_ROWS rows only:
//     g[T-1]        = 1 + (1-w)            = 2 - w
//     g[r] (middle) = -(1-w)^2 * w^(T-2-r)
//     g[rlo]        = -(1-w)   * w^(T-2-rlo)   (absorbs truncated tail)
// w = 0.9 => keeping 256 rows has truncation error ~1e-12 (f32-exact).
// Single fused kernel: 512 blocks x 256 thr; block = 8 float4 cols x 32
// row-groups; LDS tree-reduce across groups. No workspace, one launch.

#define WEMA 0.9f
#define KEEP_ROWS 256
#define C4 8          // float4 columns per block
#define GROUPS 32     // row groups per block (C4 * GROUPS = 256 threads)

__global__ __launch_bounds__(256) void ema_fused(const float* __restrict__ x,
                                                 float* __restrict__ out,
                                                 int T, int N4, int rlo) {
    __shared__ float4 part[GROUPS][C4 + 1];   // +1 pad: avoid 8-way bank conflict
    const int t = threadIdx.x;
    const int c = t & (C4 - 1);
    const int g = t >> 3;                     // log2(C4)
    const int col4 = blockIdx.x * C4 + c;

    const int rows = T - rlo;
    const int rpg = (rows + GROUPS - 1) / GROUPS;   // rows per group (8)
    const int rbeg = rlo + g * rpg;
    int rend = rbeg + rpg; if (rend > T) rend = T;

    const float4* __restrict__ x4 = reinterpret_cast<const float4*>(x);
    float4 acc = make_float4(0.f, 0.f, 0.f, 0.f);

    if (col4 < N4) {
        // middle coefficient at rbeg, advanced by *(1/w) per row
        const float one_m_w = 1.0f - WEMA;
        float cmid = -one_m_w * one_m_w * __powf(WEMA, (float)(T - 2 - rbeg));
        const float invw = 1.0f / WEMA;
        #pragma unroll 4
        for (int r = rbeg; r < rend; ++r) {
            float gc = cmid;
            if (r == rlo)   gc = -one_m_w * __powf(WEMA, (float)(T - 2 - r));
            if (r == T - 1) gc = 2.0f - WEMA;
            float4 v = x4[(size_t)r * N4 + col4];
            acc.x = fmaf(gc, v.x, acc.x);
            acc.y = fmaf(gc, v.y, acc.y);
            acc.z = fmaf(gc, v.z, acc.z);
            acc.w = fmaf(gc, v.w, acc.w);
            cmid *= invw;
        }
    }

    part[g][c] = acc;
    __syncthreads();
    #pragma unroll
    for (int s = GROUPS >> 1; s > 0; s >>= 1) {
        if (g < s) {
            float4 o = part[g + s][c];
            float4 m = part[g][c];
            m.x += o.x; m.y += o.y; m.z += o.z; m.w += o.w;
            part[g][c] = m;
        }
        __syncthreads();
    }
    if (g == 0 && col4 < N4) {
        reinterpret_cast<float4*>(out)[col4] = part[0][c];
    }
}

extern "C" void kernel_launch(void* const* d_in, const int* in_sizes, int n_in,
                              void* d_out, int out_size, void* d_ws, size_t ws_size,
                              hipStream_t stream) {
    const float* x = (const float*)d_in[0];
    float* out = (float*)d_out;

    const int N = out_size;                 // 16384
    const int T = in_sizes[0] / N;          // 4096
    const int N4 = N >> 2;                  // 4096

    int rlo = T - KEEP_ROWS;
    if (rlo < 0) rlo = 0;

    const int grid = (N4 + C4 - 1) / C4;    // 512 blocks
    ema_fused<<<grid, 256, 0, stream>>>(x, out, T, N4, rlo);
}